// Round 7
// baseline (328.067 us; speedup 1.0000x reference)
//
#include <hip/hip_runtime.h>

// ---------------- problem constants ----------------
#define NBATCH 4
#define SEQ    4096
#define DMODEL 512
#define NHEAD  8
#define HDIM   64
#define NSN    32
#define NXT    2048
#define QLEN   2080   // NXT + NSN
#define KLEN   4128   // SEQ + NSN

using bf16x8 = __attribute__((ext_vector_type(8))) short;
using f32x4  = __attribute__((ext_vector_type(4))) float;

typedef __attribute__((address_space(1))) unsigned int gu32;
typedef __attribute__((address_space(3))) unsigned int lu32;

// Q projection pre-scale: SCALE * log2(e) — softmax runs in exp2 domain
#define QSCALE 0.18033688f

__device__ __forceinline__ unsigned short f2bf(float f) {
  unsigned int u = __float_as_uint(f);
  u += 0x7FFF + ((u >> 16) & 1);          // RTNE
  return (unsigned short)(u >> 16);
}

__device__ __forceinline__ f32x4 mfma16(bf16x8 a, bf16x8 b, f32x4 c) {
  return __builtin_amdgcn_mfma_f32_16x16x32_bf16(a, b, c, 0, 0, 0);
}

__device__ __forceinline__ void gload_lds16(const void* g, void* lds_base) {
  __builtin_amdgcn_global_load_lds((const gu32*)g, (lu32*)lds_base, 16, 0, 0);
}

// DPP 16-lane reductions (VALU only)
template <int C>
__device__ __forceinline__ float fmax_dpp(float v) {
  int o = __builtin_amdgcn_update_dpp(0, __float_as_int(v), C, 0xF, 0xF, false);
  return fmaxf(v, __int_as_float(o));
}
__device__ __forceinline__ float red_max16(float v) {
  v = fmax_dpp<0xB1>(v);   // quad_perm xor1
  v = fmax_dpp<0x4E>(v);   // quad_perm xor2
  v = fmax_dpp<0x141>(v);  // row_half_mirror
  v = fmax_dpp<0x140>(v);  // row_mirror
  return v;
}

// ---------------- fp32 -> bf16 converts ----------------
__global__ __launch_bounds__(256) void cvt_f32_bf16_v4(const float* __restrict__ src,
                                                       unsigned short* __restrict__ dst, int n4) {
  int i = blockIdx.x * 256 + threadIdx.x;
  if (i >= n4) return;
  float4 v = reinterpret_cast<const float4*>(src)[i];
  ushort4 r;
  r.x = f2bf(v.x); r.y = f2bf(v.y); r.z = f2bf(v.z); r.w = f2bf(v.w);
  reinterpret_cast<ushort4*>(dst)[i] = r;
}

__global__ __launch_bounds__(256) void cvt_w4(const float* __restrict__ a, const float* __restrict__ b,
                                              const float* __restrict__ c, const float* __restrict__ d,
                                              unsigned short* __restrict__ dst) {
  const float* s = blockIdx.y == 0 ? a : blockIdx.y == 1 ? b : blockIdx.y == 2 ? c : d;
  int i = blockIdx.x * 256 + threadIdx.x;   // 65536 float4 per matrix
  float4 v = reinterpret_cast<const float4*>(s)[i];
  ushort4 r;
  r.x = f2bf(v.x); r.y = f2bf(v.y); r.z = f2bf(v.z); r.w = f2bf(v.w);
  reinterpret_cast<ushort4*>(dst)[(size_t)blockIdx.y * 65536 + i] = r;
}

// ---------------- seq projection GEMM (m97 structure, known-good) ----------------
__global__ __launch_bounds__(256) void proj_gemm(const unsigned short* __restrict__ X,
                                                 const unsigned short* __restrict__ W,
                                                 unsigned short* __restrict__ Out,
                                                 int rpb_shift, int row_off, int out_L, float scale) {
  __shared__ unsigned short As[128 * 32];
  __shared__ unsigned short Bs[128 * 32];
  const int tid = threadIdx.x;
  const int w = tid >> 6, l = tid & 63;
  const int lg = l >> 4, lr = l & 15;
  const int row0 = blockIdx.x * 128, col0 = blockIdx.y * 128;
  const int wr = (w >> 1) * 64, wc = (w & 1) * 64;
  const int mask = (1 << rpb_shift) - 1;

  f32x4 acc[4][4];
#pragma unroll
  for (int m = 0; m < 4; ++m)
#pragma unroll
    for (int n = 0; n < 4; ++n) acc[m][n] = (f32x4){0.f, 0.f, 0.f, 0.f};

  const int sr = w * 16 + (l >> 2);
  const int sc = (l & 3) * 8;

  for (int k0 = 0; k0 < 512; k0 += 32) {
#pragma unroll
    for (int i = 0; i < 2; ++i) {
      int gr = row0 + sr + i * 64;
      int xrow = ((gr >> rpb_shift) << 12) + row_off + (gr & mask);
      const unsigned short* gpa = X + (size_t)xrow * 512 + k0 + sc;
      gload_lds16(gpa, (char*)As + i * 4096 + w * 1024);
      const unsigned short* gpb = W + (size_t)(col0 + sr + i * 64) * 512 + k0 + sc;
      gload_lds16(gpb, (char*)Bs + i * 4096 + w * 1024);
    }
    __syncthreads();
    bf16x8 av[4], bv[4];
#pragma unroll
    for (int m = 0; m < 4; ++m) av[m] = *(const bf16x8*)&As[(wr + m * 16 + lr) * 32 + lg * 8];
#pragma unroll
    for (int n = 0; n < 4; ++n) bv[n] = *(const bf16x8*)&Bs[(wc + n * 16 + lr) * 32 + lg * 8];
#pragma unroll
    for (int m = 0; m < 4; ++m)
#pragma unroll
      for (int n = 0; n < 4; ++n) acc[m][n] = mfma16(av[m], bv[n], acc[m][n]);
    __syncthreads();
  }

#pragma unroll
  for (int m = 0; m < 4; ++m) {
    int crow = row0 + wr + m * 16 + lg * 4;
#pragma unroll
    for (int n = 0; n < 4; ++n) {
      int ccol = col0 + wc + n * 16 + lr;
      int hh = ccol >> 6, dd = ccol & 63;
#pragma unroll
      for (int r = 0; r < 4; ++r) {
        int cr = crow + r;
        int bb = cr >> rpb_shift, ii = cr & mask;
        Out[(((size_t)bb * NHEAD + hh) * out_L + ii) * HDIM + dd] = f2bf(acc[m][n][r] * scale);
      }
    }
  }
}

// ---------------- ns projections ----------------
__global__ __launch_bounds__(256) void ns_proj(const float* __restrict__ nst,
                                               const float* __restrict__ Wnq, const float* __restrict__ Wnk,
                                               const float* __restrict__ Wnv,
                                               unsigned short* __restrict__ Qb, unsigned short* __restrict__ Kb,
                                               unsigned short* __restrict__ Vb) {
  const int oc = blockIdx.x, n = blockIdx.y, p = blockIdx.z;
  const float* W = p == 0 ? Wnq : p == 1 ? Wnk : Wnv;
  unsigned short* Out = p == 0 ? Qb : p == 1 ? Kb : Vb;
  const int out_L = p == 0 ? QLEN : KLEN;
  const int orow = p == 0 ? NXT + n : SEQ + n;
  const float scale = p == 0 ? QSCALE : 1.f;

  __shared__ float xs[NBATCH][DMODEL];
  __shared__ float red[NBATCH][128];
  const int tid = threadIdx.x;
  for (int idx = tid; idx < NBATCH * DMODEL; idx += 256)
    xs[idx >> 9][idx & 511] = nst[(size_t)((idx >> 9) * NSN + n) * DMODEL + (idx & 511)];
  __syncthreads();

  const int o = oc * 128 + (tid & 127);
  const int dh = tid >> 7;
  float a0 = 0.f, a1 = 0.f, a2 = 0.f, a3 = 0.f;
  const float* wp = W + (size_t)n * DMODEL * DMODEL + o;
#pragma unroll 8
  for (int d = dh * 256; d < dh * 256 + 256; ++d) {
    float wv = wp[(size_t)d * DMODEL];
    a0 += xs[0][d] * wv; a1 += xs[1][d] * wv; a2 += xs[2][d] * wv; a3 += xs[3][d] * wv;
  }
  if (dh == 1) { red[0][tid & 127] = a0; red[1][tid & 127] = a1; red[2][tid & 127] = a2; red[3][tid & 127] = a3; }
  __syncthreads();
  if (dh == 0) {
    a0 += red[0][tid & 127]; a1 += red[1][tid & 127]; a2 += red[2][tid & 127]; a3 += red[3][tid & 127];
    int hh = o >> 6, dd = o & 63;
    float v[4] = {a0, a1, a2, a3};
#pragma unroll
    for (int b = 0; b < NBATCH; ++b)
      Out[(((size_t)b * NHEAD + hh) * out_L + orow) * HDIM + dd] = f2bf(v[b] * scale);
  }
}

// ---------------- global V transpose: Vt[bh][d][kv] = V[bh][kv][d] ----------------
__global__ __launch_bounds__(256) void vtrans(const unsigned short* __restrict__ V,
                                              unsigned short* __restrict__ Vt) {
  __shared__ unsigned short t[64 * 64];
  const int tid = threadIdx.x;
  const int kv0 = blockIdx.x * 64, bh = blockIdx.y;
  const unsigned short* Vhp = V + (size_t)bh * KLEN * HDIM;
  unsigned short* Vtp = Vt + (size_t)bh * HDIM * KLEN;

#pragma unroll
  for (int i = 0; i < 2; ++i) {
    int c = i * 256 + tid;             // 512 chunks of 16B: row = kv-local, c8 = d-chunk
    int row = c >> 3, c8 = c & 7;
    int kvg = kv0 + row; if (kvg > KLEN - 1) kvg = KLEN - 1;
    int4 v4 = *(const int4*)(Vhp + (size_t)kvg * HDIM + c8 * 8);
    *(int4*)&t[row * 64 + ((c8 ^ ((row >> 3) & 7)) * 8)] = v4;
  }
  __syncthreads();
#pragma unroll
  for (int i = 0; i < 2; ++i) {
    int c = i * 256 + tid;             // 512: d row, k8 = kv-chunk
    int d = c >> 3, k8 = c & 7;
    if (kv0 + k8 * 8 <= KLEN - 8) {
      unsigned int wd[4];
#pragma unroll
      for (int jj = 0; jj < 4; ++jj) {
        int ka = k8 * 8 + jj * 2, kb2 = ka + 1;
        unsigned int lo = t[ka  * 64 + (((d >> 3) ^ ((ka  >> 3) & 7)) * 8) + (d & 7)];
        unsigned int hi = t[kb2 * 64 + (((d >> 3) ^ ((kb2 >> 3) & 7)) * 8) + (d & 7)];
        wd[jj] = lo | (hi << 16);
      }
      int4 o; o.x = wd[0]; o.y = wd[1]; o.z = wd[2]; o.w = wd[3];
      *(int4*)(Vtp + (size_t)d * KLEN + kv0 + k8 * 8) = o;
    }
  }
}

// ---------------- flash attention ----------------
// R7: 8 waves (512 thr), QBLK=128 q-rows/block -> K/V tiles amortized over 8 waves;
// LDS 48KB -> 3 blocks/CU = 24 waves/CU. Staging: waves 0-3 DMA K, waves 4-7 DMA V.
// lsum via ones-MFMA (B=all-ones -> every lane gets its q-row sum); QK^T C seeded
// with -m so p=exp2(s) directly (subs only in the rare grow branch).
__global__ __launch_bounds__(512) void attn_kernel(const unsigned short* __restrict__ Qb,
                                                   const unsigned short* __restrict__ Kb,
                                                   const unsigned short* __restrict__ Vtg,
                                                   unsigned short* __restrict__ Att) {
  __shared__ unsigned short Ks[2][64 * 64];   // 8 KB x2, [kv][d] swizzled
  __shared__ unsigned short Vs[2][64 * 64];   // 8 KB x2, [d][kv] swizzled
  __shared__ unsigned short Ps[8][16 * 64];   // 2 KB x8, per-wave [q][kv] swizzled

  const int tid = threadIdx.x;
  const int w = tid >> 6, l = tid & 63;
  const int lg = l >> 4, lr = l & 15;
  const int qb = 16 - (int)blockIdx.x;                 // big blocks first
  const int bh = (int)blockIdx.z * NHEAD + (int)blockIdx.y;
  const int q0 = qb * 128;
  const int basew = NXT + q0 + w * 16;                 // abs key-pos of this wave's q row 0
  int nkb = ((NXT + q0) >> 6) + 2;                     // tiles incl. partial diag
  if (nkb > KLEN / 64 + 1) nkb = KLEN / 64 + 1;        // cap at 65 (keys end at 4127)
  const int kbm = basew >> 6;                          // first tile needing causal mask

  const unsigned short* Qh = Qb + (size_t)bh * QLEN * HDIM;
  const unsigned short* Kh = Kb + (size_t)bh * KLEN * HDIM;
  const unsigned short* Vh = Vtg + (size_t)bh * HDIM * KLEN;   // [64][KLEN]

  int qrow = q0 + w * 16 + lr; if (qrow > QLEN - 1) qrow = QLEN - 1;
  const bf16x8 qa0 = *(const bf16x8*)(Qh + (size_t)qrow * HDIM + lg * 8);
  const bf16x8 qa1 = *(const bf16x8*)(Qh + (size_t)qrow * HDIM + 32 + lg * 8);

  f32x4 acc[4];
#pragma unroll
  for (int n = 0; n < 4; ++n) acc[n] = (f32x4){0.f, 0.f, 0.f, 0.f};
  float m_r[4], lsum[4];
#pragma unroll
  for (int r = 0; r < 4; ++r) { m_r[r] = 0.f; lsum[r] = 0.f; }   // m biased at 0

  // all-ones bf16 B-operand for row-sum MFMA
  const bf16x8 ones = {(short)0x3F80, (short)0x3F80, (short)0x3F80, (short)0x3F80,
                       (short)0x3F80, (short)0x3F80, (short)0x3F80, (short)0x3F80};

  // staging lane geometry (involutive chunk swizzle, rule #21)
  const int rloc = l >> 3;
  const int jsrc = ((l & 7) ^ rloc) * 8;     // swizzled source col (elems)
  const int stg16 = (w & 3) * 16;            // 16-row group this wave stages
  const bool stgK = (w < 4);

#define STAGE(buf, kv0s, CLAMP)                                                     \
  {                                                                                 \
    _Pragma("unroll")                                                               \
    for (int i = 0; i < 2; ++i) {                                                   \
      const int r8 = stg16 + i * 8;                                                 \
      if (stgK) {                                                                   \
        int kr = (kv0s) + r8 + rloc;                                                \
        if (CLAMP) kr = kr > KLEN - 1 ? KLEN - 1 : kr;                              \
        gload_lds16(Kh + (size_t)kr * HDIM + jsrc, &Ks[buf][r8 * 64]);              \
      } else {                                                                      \
        int vc = (kv0s) + jsrc;                                                     \
        if (CLAMP) vc = vc > KLEN - 8 ? KLEN - 8 : vc;                              \
        gload_lds16(Vh + (size_t)(r8 + rloc) * KLEN + vc, &Vs[buf][r8 * 64]);       \
      }                                                                             \
    }                                                                               \
  }

  STAGE(0, 0, false)
  __syncthreads();
  int cur = 0;

  for (int kb = 0; kb < nkb; ++kb) {
    if (kb + 1 < nkb) {                                // prefetch next tile via DMA
      const int nv0 = (kb + 1) * 64;
      if (nv0 + 64 <= KLEN) STAGE(cur ^ 1, nv0, false)
      else                  STAGE(cur ^ 1, nv0, true)
    }

    const unsigned short* Kc = &Ks[cur][0];
    const unsigned short* Vc = &Vs[cur][0];

    // S = Q K^T - m  (C seeded with -m_r): 16 q-rows x 64 keys per wave
    const f32x4 minit = {-m_r[0], -m_r[1], -m_r[2], -m_r[3]};
    f32x4 s[4];
#pragma unroll
    for (int n = 0; n < 4; ++n) {
      const int rk = n * 16 + lr;
      const bf16x8 k0 = *(const bf16x8*)&Kc[rk * 64 + ((lg ^ (rk & 7)) * 8)];
      const bf16x8 k1 = *(const bf16x8*)&Kc[rk * 64 + (((4 + lg) ^ (rk & 7)) * 8)];
      s[n] = mfma16(qa0, k0, minit);
      s[n] = mfma16(qa1, k1, s[n]);
    }

    if (kb >= kbm) {                                   // causal mask (near-diag tiles)
      const int kv0 = kb * 64;
      const int qa_base = basew + lg * 4;
#pragma unroll
      for (int n = 0; n < 4; ++n) {
        const int kc = kv0 + n * 16 + lr;
#pragma unroll
        for (int r = 0; r < 4; ++r)
          if (kc > qa_base + r) s[n][r] = -1e30f;
      }
    }

    // online softmax (exp2 domain, biased): DPP max, subs only on grow
    float rmax[4];
#pragma unroll
    for (int r = 0; r < 4; ++r)
      rmax[r] = red_max16(fmaxf(fmaxf(s[0][r], s[1][r]), fmaxf(s[2][r], s[3][r])));
    int grow = (rmax[0] > 11.5f) | (rmax[1] > 11.5f) |
               (rmax[2] > 11.5f) | (rmax[3] > 11.5f);
    if (__any(grow)) {                                 // T13 defer-max
      float dl[4];
#pragma unroll
      for (int r = 0; r < 4; ++r) {
        dl[r] = fmaxf(rmax[r], 0.f);
        float sc = exp2f(-dl[r]);
        lsum[r] *= sc; m_r[r] += dl[r];
#pragma unroll
        for (int n = 0; n < 4; ++n) acc[n][r] *= sc;
      }
#pragma unroll
      for (int n = 0; n < 4; ++n)
#pragma unroll
        for (int r = 0; r < 4; ++r) s[n][r] = exp2f(s[n][r] - dl[r]);
    } else {
#pragma unroll
      for (int n = 0; n < 4; ++n)
#pragma unroll
        for (int r = 0; r < 4; ++r) s[n][r] = exp2f(s[n][r]);
    }

    // P -> LDS (per-wave, swizzled [q][kv]), round-half-up to bf16
    unsigned short* Pw = &Ps[w][0];
#pragma unroll
    for (int n = 0; n < 4; ++n)
#pragma unroll
      for (int r = 0; r < 4; ++r) {
        unsigned int u = __float_as_uint(s[n][r]) + 0x8000u;
        const int q = lg * 4 + r;
        const int kc = n * 2 + (lr >> 3);
        Pw[q * 64 + ((kc ^ (q & 7)) * 8) + (lr & 7)] = (unsigned short)(u >> 16);
      }
    asm volatile("s_waitcnt lgkmcnt(0)" ::: "memory");
    __builtin_amdgcn_sched_barrier(0);                 // rule #18
    bf16x8 pa[2];
#pragma unroll
    for (int ks = 0; ks < 2; ++ks)
      pa[ks] = *(const bf16x8*)&Pw[lr * 64 + (((ks * 4 + lg) ^ (lr & 7)) * 8)];

    // PV + row-sum via ones-MFMA
    f32x4 acc_s = (f32x4){0.f, 0.f, 0.f, 0.f};
    acc_s = mfma16(pa[0], ones, acc_s);
    acc_s = mfma16(pa[1], ones, acc_s);
#pragma unroll
    for (int n = 0; n < 4; ++n) {
      const int rv = n * 16 + lr;
#pragma unroll
      for (int ks = 0; ks < 2; ++ks) {
        const bf16x8 vv = *(const bf16x8*)&Vc[rv * 64 + (((ks * 4 + lg) ^ (rv & 7)) * 8)];
        acc[n] = mfma16(pa[ks], vv, acc[n]);
      }
    }
#pragma unroll
    for (int r = 0; r < 4; ++r) lsum[r] += acc_s[r];

    __syncthreads();   // readers of buf[cur] done; next tile's DMA drained
    cur ^= 1;
  }

  float inv[4];
#pragma unroll
  for (int r = 0; r < 4; ++r) inv[r] = 1.f / lsum[r];
#pragma unroll
  for (int n = 0; n < 4; ++n)
#pragma unroll
    for (int r = 0; r < 4; ++r) {
      int qi = q0 + w * 16 + lg * 4 + r;
      if (qi < QLEN)
        Att[((size_t)blockIdx.z * QLEN + qi) * DMODEL + blockIdx.y * HDIM + n * 16 + lr] =
            f2bf(acc[n][r] * inv[r]);
    }
#undef STAGE
}

// ---------------- output GEMM (unchanged) ----------------
__global__ __launch_bounds__(256) void out_gemm(const unsigned short* __restrict__ A,
                                                const unsigned short* __restrict__ W,
                                                float* __restrict__ Out) {
  __shared__ unsigned short As[128 * 32];
  __shared__ unsigned short Bs[128 * 32];
  const int tid = threadIdx.x;
  const int w = tid >> 6, l = tid & 63;
  const int lg = l >> 4, lr = l & 15;
  const int row0 = blockIdx.x * 128, col0 = blockIdx.y * 128;
  const int wr = (w >> 1) * 64, wc = (w & 1) * 64;

  f32x4 acc[4][4];
#pragma unroll
  for (int m = 0; m < 4; ++m)
#pragma unroll
    for (int n = 0; n < 4; ++n) acc[m][n] = (f32x4){0.f, 0.f, 0.f, 0.f};

  const int sr = w * 16 + (l >> 2);
  const int sc = (l & 3) * 8;

  for (int k0 = 0; k0 < 512; k0 += 32) {
#pragma unroll
    for (int i = 0; i < 2; ++i) {
      const unsigned short* gpa = A + (size_t)(row0 + sr + i * 64) * 512 + k0 + sc;
      gload_lds16(gpa, (char*)As + i * 4096 + w * 1024);
      const unsigned short* gpb = W + (size_t)(col0 + sr + i * 64) * 512 + k0 + sc;
      gload_lds16(gpb, (char*)Bs + i * 4096 + w * 1024);
    }
    __syncthreads();
    bf16x8 av[4], bv[4];
#pragma unroll
    for (int m = 0; m < 4; ++m) av[m] = *(const bf16x8*)&As[(wr + m * 16 + lr) * 32 + lg * 8];
#pragma unroll
    for (int n = 0; n < 4; ++n) bv[n] = *(const bf16x8*)&Bs[(wc + n * 16 + lr) * 32 + lg * 8];
#pragma unroll
    for (int m = 0; m < 4; ++m)
#pragma unroll
      for (int n = 0; n < 4; ++n) acc[m][n] = mfma16(av[m], bv[n], acc[m][n]);
    __syncthreads();
  }

#pragma unroll
  for (int m = 0; m < 4; ++m) {
    int crow = row0 + wr + m * 16 + lg * 4;
#pragma unroll
    for (int n = 0; n < 4; ++n) {
      int ccol = col0 + wc + n * 16 + lr;
#pragma unroll
      for (int r = 0; r < 4; ++r) {
        int cr = crow + r;
        int bb = cr / QLEN, ii = cr - bb * QLEN;
        size_t off = ii < NXT
                       ? ((size_t)bb * NXT + ii) * DMODEL + ccol
                       : (size_t)NBATCH * NXT * DMODEL + ((size_t)bb * NSN + (ii - NXT)) * DMODEL + ccol;
        Out[off] = acc[m][n][r];
      }
    }
  }
}

// ---------------- host launch ----------------
extern "C" void kernel_launch(void* const* d_in, const int* in_sizes, int n_in,
                              void* d_out, int out_size, void* d_ws, size_t ws_size,
                              hipStream_t stream) {
  const float* seq = (const float*)d_in[0];
  const float* nst = (const float*)d_in[2];
  const float* Wq  = (const float*)d_in[5];
  const float* Wk  = (const float*)d_in[6];
  const float* Wv  = (const float*)d_in[7];
  const float* nsq = (const float*)d_in[8];
  const float* nsk = (const float*)d_in[9];
  const float* nsv = (const float*)d_in[10];
  const float* Wo  = (const float*)d_in[11];
  float* out = (float*)d_out;

  // fully disjoint workspace layout (no aliasing)
  char* ws = (char*)d_ws;
  unsigned short* Xbf  = (unsigned short*)(ws);                       // 16,777,216
  unsigned short* Wqb  = (unsigned short*)(ws + 16777216);            // 524,288 x4
  unsigned short* Wkb  = Wqb + 262144;
  unsigned short* Wvb  = Wkb + 262144;
  unsigned short* Wob  = Wvb + 262144;
  unsigned short* Qbuf = (unsigned short*)(ws + 18874368);            // 8,519,680
  unsigned short* Kbuf = (unsigned short*)(ws + 27394048);            // 16,908,288
  unsigned short* Vbuf = (unsigned short*)(ws + 44302336);            // 16,908,288
  unsigned short* Att  = (unsigned short*)(ws + 61210624);            // 8,519,680
  unsigned short* Vtg  = (unsigned short*)(ws + 69730304);            // 16,908,288 -> total 86,638,592
  if (ws_size < 86638592) return;   // insufficient scratch -> visible first-call failure

  cvt_f32_bf16_v4<<<dim3(8192), dim3(256), 0, stream>>>(seq, Xbf, 2097152);
  cvt_w4<<<dim3(256, 4), dim3(256), 0, stream>>>(Wq, Wk, Wv, Wo, Wqb);
  proj_gemm<<<dim3(128, 4), dim3(256), 0, stream>>>(Xbf, Wkb, Kbuf, 12, 0, KLEN, 1.f);
  proj_gemm<<<dim3(128, 4), dim3(256), 0, stream>>>(Xbf, Wvb, Vbuf, 12, 0, KLEN, 1.f);
  proj_gemm<<<dim3(64, 4), dim3(256), 0, stream>>>(Xbf, Wqb, Qbuf, 11, 2048, QLEN, QSCALE);
  ns_proj<<<dim3(4, 32, 3), dim3(256), 0, stream>>>(nst, nsq, nsk, nsv, Qbuf, Kbuf, Vbuf);
  vtrans<<<dim3(65, 32), dim3(256), 0, stream>>>(Vbuf, Vtg);
  attn_kernel<<<dim3(17, 8, 4), dim3(512), 0, stream>>>(Qbuf, Kbuf, Vtg, Att);
  out_gemm<<<dim3(65, 4), dim3(256), 0, stream>>>(Att, Wob, out);
}